// Round 4
// baseline (622.815 us; speedup 1.0000x reference)
//
#include <hip/hip_runtime.h>

#define NN 100000
#define NE 1600000
#define NEPAD 2300000   // NE + 7*NN: 8-padded CSR upper bound
#define NB 1563         // ceil(NN/64) buckets of 64 nodes

typedef _Float16 f16x8 __attribute__((ext_vector_type(8)));
typedef float f32x4 __attribute__((ext_vector_type(4)));

// ---------------- workspace layout (bytes) ----------------
static const size_t OFF_CNT   = 0;                         // N ints
static const size_t OFF_RP    = OFF_CNT   + 400128;        // N+1 ints (8-padded offsets)
static const size_t OFF_CUR   = OFF_RP    + 400128;        // N ints
static const size_t OFF_BS    = OFF_CUR   + 400128;        // 128 ints
static const size_t OFF_INVD  = OFF_BS    + 512;           // N floats
static const size_t OFF_BCUR  = OFF_INVD  + 400128;        // NB ints
static const size_t OFF_SSRC  = OFF_BCUR  + 6400;          // NEPAD ints
static const size_t OFF_PAIRS = OFF_SSRC  + 9200000;       // NEPAD int2
static const size_t OFF_B1    = OFF_PAIRS + 18400000;      // 128x256 f16
static const size_t OFF_B2    = OFF_B1    + 65536;
static const size_t OFF_X16   = OFF_B2    + 65536;         // (N+1)*128 f16 (row N = zeros)
static const size_t OFF_H16   = OFF_X16   + 25600256;      // (N+1)*128 f16 (row N = zeros)
static const size_t OFF_AGG   = OFF_H16   + 25600256;      // N*128 f16
// total ~106.1 MB (round-1 layout proved >=110.4 MB available)

static __device__ inline float h2f(uint bits) {
    return (float)__builtin_bit_cast(_Float16, (ushort)bits);
}
static __device__ inline ushort f2h(float f) {
    return __builtin_bit_cast(ushort, (_Float16)f);
}
static __device__ inline uint pk2h(float a, float b) {
    return (uint)f2h(a) | ((uint)f2h(b) << 16);
}

__global__ void zero_i32(int* __restrict__ p, int n) {
    int i = blockIdx.x * blockDim.x + threadIdx.x;
    if (i < n) p[i] = 0;
}

__global__ void fill_pad(int* __restrict__ ssrc) {
    int i = blockIdx.x * blockDim.x + threadIdx.x;
    if (i < NEPAD) ssrc[i] = NN;
}

__global__ void zero_dummy(ushort* __restrict__ a, ushort* __restrict__ b) {
    int t = threadIdx.x;
    a[(size_t)NN * 128 + t] = 0;
    b[(size_t)NN * 128 + t] = 0;
}

__global__ void count_k(const int* __restrict__ dst, int* __restrict__ cnt, int ne) {
    int e = blockIdx.x * blockDim.x + threadIdx.x;
    if (e < ne) atomicAdd(&cnt[dst[e]], 1);
}

// exclusive scan of 8-padded counts within 1024-blocks
__global__ void scan_blocks(const int* __restrict__ cnt, int* __restrict__ rp,
                            int* __restrict__ blockSum, int n) {
    __shared__ int s[1024];
    int t = threadIdx.x;
    int gid = blockIdx.x * 1024 + t;
    int v = (gid < n) ? ((cnt[gid] + 7) & ~7) : 0;
    s[t] = v;
    __syncthreads();
    for (int off = 1; off < 1024; off <<= 1) {
        int x = (t >= off) ? s[t - off] : 0;
        __syncthreads();
        s[t] += x;
        __syncthreads();
    }
    if (gid < n) rp[gid] = s[t] - v;
    if (t == 1023) blockSum[blockIdx.x] = s[1023];
}

__global__ void scan_sums(int* __restrict__ blockSum, int nb) {
    __shared__ int s[128];
    int t = threadIdx.x;
    int v = (t < nb) ? blockSum[t] : 0;
    s[t] = v;
    __syncthreads();
    for (int off = 1; off < 128; off <<= 1) {
        int x = (t >= off) ? s[t - off] : 0;
        __syncthreads();
        s[t] += x;
        __syncthreads();
    }
    if (t < nb) blockSum[t] = s[t] - v;
}

__global__ void scan_add(int* __restrict__ rp, const int* __restrict__ blockSum,
                         const int* __restrict__ cnt, int* __restrict__ cursor,
                         float* __restrict__ inv_deg, int n) {
    int gid = blockIdx.x * blockDim.x + threadIdx.x;
    if (gid < n) {
        int v = rp[gid] + blockSum[gid >> 10];
        rp[gid] = v;
        cursor[gid] = v;
        int d = cnt[gid];
        inv_deg[gid] = 1.0f / (float)(d > 1 ? d : 1);
        if (gid == n - 1) rp[n] = v + ((d + 7) & ~7);
    }
}

__global__ void init_bcur(const int* __restrict__ rp, int* __restrict__ bcur) {
    int b = blockIdx.x * blockDim.x + threadIdx.x;
    if (b < NB) bcur[b] = rp[b << 6];
}

// pass A: scatter (src,dst) pairs into per-bucket windows (write-local)
__global__ void scatter_pairs(const int* __restrict__ src, const int* __restrict__ dst,
                              int* __restrict__ bcur, int2* __restrict__ pairs, int ne) {
    int e = blockIdx.x * blockDim.x + threadIdx.x;
    if (e < ne) {
        int d = dst[e];
        int p = atomicAdd(&bcur[d >> 6], 1);
        int2 pr; pr.x = src[e]; pr.y = d;
        pairs[p] = pr;
    }
}

// pass B: within each bucket, scatter src into the node-exact CSR slot
__global__ __launch_bounds__(256) void fill_local(const int* __restrict__ rp,
                                                  const int* __restrict__ bcur,
                                                  const int2* __restrict__ pairs,
                                                  int* __restrict__ cursor,
                                                  int* __restrict__ ssrc) {
    int b = blockIdx.x;
    int beg = rp[b << 6];
    int end = bcur[b];
    for (int i = beg + threadIdx.x; i < end; i += 256) {
        int2 pr = pairs[i];
        int p = atomicAdd(&cursor[pr.y], 1);
        ssrc[p] = pr.x;
    }
}

// fp32 [n][128] -> f16 [n][128]
__global__ void to_f16(const float* __restrict__ in, ushort* __restrict__ out, int n4) {
    int i = blockIdx.x * blockDim.x + threadIdx.x;
    if (i < n4) {
        float4 v = ((const float4*)in)[i];
        uint2 o;
        o.x = pk2h(v.x, v.y);
        o.y = pk2h(v.z, v.w);
        ((uint2*)out)[i] = o;
    }
}

// pack [Wl;Wr] into Bt f16 [n][k'=256]
__global__ void prep_w(const float* __restrict__ Wl, const float* __restrict__ Wr,
                       ushort* __restrict__ Bt) {
    int id = blockIdx.x * blockDim.x + threadIdx.x;
    if (id >= 32768) return;
    int nw = id & 127;
    int km = id >> 7;
    const float* W = (km < 128) ? Wl : Wr;
    int k = km & 127;
    Bt[(size_t)nw * 256 + km] = f2h(W[k * 128 + nw]);
}

// one wave per node; 8 gathers in flight; pad slots hit zero row NN
__global__ __launch_bounds__(256) void aggregate16(const ushort* __restrict__ feat,
                                                   const int* __restrict__ rp,
                                                   const int* __restrict__ ssrc,
                                                   const float* __restrict__ inv_deg,
                                                   ushort* __restrict__ outv, int n) {
    int wave = (blockIdx.x * blockDim.x + threadIdx.x) >> 6;
    int lane = threadIdx.x & 63;
    if (wave >= n) return;
    int beg = rp[wave], end = rp[wave + 1];
    const size_t loff = (size_t)(lane * 2);
    float s0 = 0.f, s1 = 0.f, s2 = 0.f, s3 = 0.f, s4 = 0.f, s5 = 0.f, s6 = 0.f, s7 = 0.f;
    int e = beg;
    if (e < end) {
        int4 c0 = *(const int4*)(ssrc + e);
        int4 c1 = *(const int4*)(ssrc + e + 4);
        for (; e < end; e += 8) {
            int4 d0 = c0, d1 = c1;
            int pn = (e + 8 < end) ? e + 8 : e;   // branchless prefetch addr
            c0 = *(const int4*)(ssrc + pn);
            c1 = *(const int4*)(ssrc + pn + 4);
            uint v0 = *(const uint*)(feat + (size_t)d0.x * 128 + loff);
            uint v1 = *(const uint*)(feat + (size_t)d0.y * 128 + loff);
            uint v2 = *(const uint*)(feat + (size_t)d0.z * 128 + loff);
            uint v3 = *(const uint*)(feat + (size_t)d0.w * 128 + loff);
            uint v4 = *(const uint*)(feat + (size_t)d1.x * 128 + loff);
            uint v5 = *(const uint*)(feat + (size_t)d1.y * 128 + loff);
            uint v6 = *(const uint*)(feat + (size_t)d1.z * 128 + loff);
            uint v7 = *(const uint*)(feat + (size_t)d1.w * 128 + loff);
            s0 += h2f(v0 & 0xffffu); s1 += h2f(v0 >> 16);
            s2 += h2f(v1 & 0xffffu); s3 += h2f(v1 >> 16);
            s0 += h2f(v2 & 0xffffu); s1 += h2f(v2 >> 16);
            s2 += h2f(v3 & 0xffffu); s3 += h2f(v3 >> 16);
            s4 += h2f(v4 & 0xffffu); s5 += h2f(v4 >> 16);
            s6 += h2f(v5 & 0xffffu); s7 += h2f(v5 >> 16);
            s4 += h2f(v6 & 0xffffu); s5 += h2f(v6 >> 16);
            s6 += h2f(v7 & 0xffffu); s7 += h2f(v7 >> 16);
        }
    }
    float id = inv_deg[wave];
    *(uint*)&outv[(size_t)wave * 128 + loff] =
        pk2h((s0 + s2 + s4 + s6) * id, (s1 + s3 + s5 + s7) * id);
}

// relu(Aop@Wl + Xop@Wr + bias) via f16 MFMA; 128x128 tile, 4 waves, K'=256
// single 32KB LDS buffer + reg-staged prefetch -> 3+ blocks/CU, no tail
__global__ __launch_bounds__(256, 3) void sage_gemm_f16(const ushort* __restrict__ Aop,
                                                        const ushort* __restrict__ Xop,
                                                        const ushort* __restrict__ Bt,
                                                        const float* __restrict__ bias,
                                                        ushort* __restrict__ outH, int n) {
    __shared__ __align__(16) ushort sA[128 * 64];
    __shared__ __align__(16) ushort sB[128 * 64];
    const int t = threadIdx.x;
    const int l = t & 63;
    const int w = t >> 6;
    const int wr = (w >> 1) * 64, wc = (w & 1) * 64;
    const int rowBase = blockIdx.x * 128;
    const int sr = t >> 1, sh = t & 1;

    f32x4 acc[4][4];
#pragma unroll
    for (int i = 0; i < 4; ++i)
#pragma unroll
        for (int j = 0; j < 4; ++j) acc[i][j] = 0.0f;

    int4 rA[4], rB[4];
    int arow = rowBase + sr;
    if (arow >= n) arow = n - 1;

    auto gload = [&](int c) {
        const ushort* srcA = (c < 2) ? Aop : Xop;
        const int4* ga = (const int4*)(srcA + (size_t)arow * 128 + (c & 1) * 64 + sh * 32);
        const int4* gb = (const int4*)(Bt + (size_t)sr * 256 + c * 64 + sh * 32);
        rA[0] = ga[0]; rA[1] = ga[1]; rA[2] = ga[2]; rA[3] = ga[3];
        rB[0] = gb[0]; rB[1] = gb[1]; rB[2] = gb[2]; rB[3] = gb[3];
    };
    auto swrite = [&]() {
        char* bA = (char*)&sA[0] + sr * 128;
        char* bB = (char*)&sB[0] + sr * 128;
        const int swz = (sr & 7) << 4;
        const int b0 = sh * 64;
        *(int4*)(bA + ((b0 +  0) ^ swz)) = rA[0];
        *(int4*)(bA + ((b0 + 16) ^ swz)) = rA[1];
        *(int4*)(bA + ((b0 + 32) ^ swz)) = rA[2];
        *(int4*)(bA + ((b0 + 48) ^ swz)) = rA[3];
        *(int4*)(bB + ((b0 +  0) ^ swz)) = rB[0];
        *(int4*)(bB + ((b0 + 16) ^ swz)) = rB[1];
        *(int4*)(bB + ((b0 + 32) ^ swz)) = rB[2];
        *(int4*)(bB + ((b0 + 48) ^ swz)) = rB[3];
    };

    gload(0);
    swrite();
    __syncthreads();

    for (int c = 0; c < 4; ++c) {
        if (c < 3) gload(c + 1);   // issue next-chunk loads early

#pragma unroll
        for (int ks = 0; ks < 2; ++ks) {
            f16x8 af[4], bf[4];
#pragma unroll
            for (int i = 0; i < 4; ++i) {
                int r = wr + i * 16 + (l & 15);
                af[i] = *(const f16x8*)((char*)&sA[0] + r * 128 +
                                        ((ks * 64 + (l >> 4) * 16) ^ ((r & 7) << 4)));
                int cn = wc + i * 16 + (l & 15);
                bf[i] = *(const f16x8*)((char*)&sB[0] + cn * 128 +
                                        ((ks * 64 + (l >> 4) * 16) ^ ((cn & 7) << 4)));
            }
#pragma unroll
            for (int i = 0; i < 4; ++i)
#pragma unroll
                for (int j = 0; j < 4; ++j)
                    acc[i][j] = __builtin_amdgcn_mfma_f32_16x16x32_f16(af[i], bf[j], acc[i][j], 0, 0, 0);
        }

        __syncthreads();
        if (c < 3) {
            swrite();
            __syncthreads();
        }
    }

#pragma unroll
    for (int j = 0; j < 4; ++j) {
        int col = wc + j * 16 + (l & 15);
        float bb = bias[col];
#pragma unroll
        for (int i = 0; i < 4; ++i) {
#pragma unroll
            for (int q = 0; q < 4; ++q) {
                int row = rowBase + wr + i * 16 + (l >> 4) * 4 + q;
                if (row < n) {
                    float v = fmaxf(acc[i][j][q] + bb, 0.f);
                    outH[(size_t)row * 128 + col] = f2h(v);
                }
            }
        }
    }
}

__global__ void final_linear16(const ushort* __restrict__ H, const float* __restrict__ Wlin,
                               const float* __restrict__ blin, float* __restrict__ out, int n) {
    int r = blockIdx.x * blockDim.x + threadIdx.x;
    if (r >= n) return;
    float a0 = blin[0], a1 = blin[1];
    const ushort* hr = H + (size_t)r * 128;
    for (int c = 0; c < 128; c += 2) {
        uint v = *(const uint*)&hr[c];
        float h0 = h2f(v & 0xffffu);
        float h1 = h2f(v >> 16);
        float4 wv = *(const float4*)&Wlin[c * 2];
        a0 += h0 * wv.x + h1 * wv.z;
        a1 += h0 * wv.y + h1 * wv.w;
    }
    float2 o = {a0, a1};
    *(float2*)&out[(size_t)r * 2] = o;
}

extern "C" void kernel_launch(void* const* d_in, const int* in_sizes, int n_in,
                              void* d_out, int out_size, void* d_ws, size_t ws_size,
                              hipStream_t stream) {
    const float* x    = (const float*)d_in[0];
    const int*   ei   = (const int*)d_in[1];
    const float* W1l  = (const float*)d_in[2];
    const float* b1   = (const float*)d_in[3];
    const float* W1r  = (const float*)d_in[4];
    const float* W2l  = (const float*)d_in[5];
    const float* b2   = (const float*)d_in[6];
    const float* W2r  = (const float*)d_in[7];
    const float* Wlin = (const float*)d_in[8];
    const float* blin = (const float*)d_in[9];
    float* out = (float*)d_out;

    char* ws = (char*)d_ws;
    int*    cnt     = (int*)(ws + OFF_CNT);
    int*    row_ptr = (int*)(ws + OFF_RP);
    int*    cursor  = (int*)(ws + OFF_CUR);
    int*    bsum    = (int*)(ws + OFF_BS);
    float*  inv_deg = (float*)(ws + OFF_INVD);
    int*    bcur    = (int*)(ws + OFF_BCUR);
    int*    ssrc    = (int*)(ws + OFF_SSRC);
    int2*   pairs   = (int2*)(ws + OFF_PAIRS);
    ushort* B1c     = (ushort*)(ws + OFF_B1);
    ushort* B2c     = (ushort*)(ws + OFF_B2);
    ushort* x16     = (ushort*)(ws + OFF_X16);
    ushort* h16     = (ushort*)(ws + OFF_H16);
    ushort* agg16   = (ushort*)(ws + OFF_AGG);

    const int* src = ei;
    const int* dst = ei + NE;

    // weight packing + f16 conversion + dummy zero rows
    prep_w<<<128, 256, 0, stream>>>(W1l, W1r, B1c);
    prep_w<<<128, 256, 0, stream>>>(W2l, W2r, B2c);
    to_f16<<<(NN * 32 + 255) / 256, 256, 0, stream>>>(x, x16, NN * 32);
    zero_dummy<<<1, 128, 0, stream>>>(x16, h16);

    // CSR build (8-padded segments; bucketed 2-pass scatter for write locality)
    zero_i32<<<(NN + 255) / 256, 256, 0, stream>>>(cnt, NN);
    fill_pad<<<(NEPAD + 255) / 256, 256, 0, stream>>>(ssrc);
    count_k<<<(NE + 255) / 256, 256, 0, stream>>>(dst, cnt, NE);
    scan_blocks<<<(NN + 1023) / 1024, 1024, 0, stream>>>(cnt, row_ptr, bsum, NN);
    scan_sums<<<1, 128, 0, stream>>>(bsum, (NN + 1023) / 1024);
    scan_add<<<(NN + 255) / 256, 256, 0, stream>>>(row_ptr, bsum, cnt, cursor, inv_deg, NN);
    init_bcur<<<(NB + 255) / 256, 256, 0, stream>>>(row_ptr, bcur);
    scatter_pairs<<<(NE + 255) / 256, 256, 0, stream>>>(src, dst, bcur, pairs, NE);
    fill_local<<<NB, 256, 0, stream>>>(row_ptr, bcur, pairs, cursor, ssrc);

    // layer 1
    aggregate16<<<(NN * 64 + 255) / 256, 256, 0, stream>>>(x16, row_ptr, ssrc, inv_deg, agg16, NN);
    sage_gemm_f16<<<(NN + 127) / 128, 256, 0, stream>>>(agg16, x16, B1c, b1, h16, NN);

    // layer 2 (h2 goes into the dead x16 buffer)
    aggregate16<<<(NN * 64 + 255) / 256, 256, 0, stream>>>(h16, row_ptr, ssrc, inv_deg, agg16, NN);
    sage_gemm_f16<<<(NN + 127) / 128, 256, 0, stream>>>(agg16, h16, B2c, b2, x16, NN);

    // final linear
    final_linear16<<<(NN + 255) / 256, 256, 0, stream>>>(x16, Wlin, blin, out, NN);
}

// Round 5
// 408.510 us; speedup vs baseline: 1.5246x; 1.5246x over previous
//
#include <hip/hip_runtime.h>

#define NN 100000
#define NE 1600000
#define NEPAD 2300000   // NE + 7*NN: 8-padded CSR upper bound
#define NBUCK 196       // ceil(NN/512) buckets of 512 nodes
#define BUCKCAP 11520   // slots per bucket in pairs[] (avg 8192, +34 sigma)
#define ACHUNK 8192     // edges per partition block

typedef _Float16 f16x8 __attribute__((ext_vector_type(8)));
typedef float f32x4 __attribute__((ext_vector_type(4)));

// ---------------- workspace layout (bytes) ----------------
static const size_t OFF_CNT   = 0;                         // N ints
static const size_t OFF_RP    = OFF_CNT   + 400128;        // N+1 ints (8-padded offsets)
static const size_t OFF_CUR   = OFF_RP    + 400128;        // N ints
static const size_t OFF_BS    = OFF_CUR   + 400128;        // 128 ints
static const size_t OFF_INVD  = OFF_BS    + 512;           // N floats
static const size_t OFF_GCUR  = OFF_INVD  + 400128;        // 256 ints
static const size_t OFF_SSRC  = OFF_GCUR  + 6400;          // NEPAD ints
static const size_t OFF_PAIRS = OFF_SSRC  + 9200000;       // NBUCK*BUCKCAP int2 = 18.06MB
static const size_t OFF_B1    = OFF_PAIRS + 18400000;      // 128x256 f16
static const size_t OFF_B2    = OFF_B1    + 65536;
static const size_t OFF_X16   = OFF_B2    + 65536;         // (N+1)*128 f16 (row N = zeros)
static const size_t OFF_H16   = OFF_X16   + 25600256;      // (N+1)*128 f16 (row N = zeros)
static const size_t OFF_AGG   = OFF_H16   + 25600256;      // N*128 f16

static __device__ inline float h2f(uint bits) {
    return (float)__builtin_bit_cast(_Float16, (ushort)bits);
}
static __device__ inline ushort f2h(float f) {
    return __builtin_bit_cast(ushort, (_Float16)f);
}
static __device__ inline uint pk2h(float a, float b) {
    return (uint)f2h(a) | ((uint)f2h(b) << 16);
}

__global__ void zero_i32(int* __restrict__ p, int n) {
    int i = blockIdx.x * blockDim.x + threadIdx.x;
    if (i < n) p[i] = 0;
}

__global__ void fill_pad(int* __restrict__ ssrc) {
    int i = blockIdx.x * blockDim.x + threadIdx.x;
    if (i < NEPAD) ssrc[i] = NN;
}

__global__ void zero_dummy(ushort* __restrict__ a, ushort* __restrict__ b) {
    int t = threadIdx.x;
    a[(size_t)NN * 128 + t] = 0;
    b[(size_t)NN * 128 + t] = 0;
}

__global__ void count_k(const int* __restrict__ dst, int* __restrict__ cnt, int ne) {
    int e = blockIdx.x * blockDim.x + threadIdx.x;
    if (e < ne) atomicAdd(&cnt[dst[e]], 1);
}

// exclusive scan of 8-padded counts within 1024-blocks
__global__ void scan_blocks(const int* __restrict__ cnt, int* __restrict__ rp,
                            int* __restrict__ blockSum, int n) {
    __shared__ int s[1024];
    int t = threadIdx.x;
    int gid = blockIdx.x * 1024 + t;
    int v = (gid < n) ? ((cnt[gid] + 7) & ~7) : 0;
    s[t] = v;
    __syncthreads();
    for (int off = 1; off < 1024; off <<= 1) {
        int x = (t >= off) ? s[t - off] : 0;
        __syncthreads();
        s[t] += x;
        __syncthreads();
    }
    if (gid < n) rp[gid] = s[t] - v;
    if (t == 1023) blockSum[blockIdx.x] = s[1023];
}

__global__ void scan_sums(int* __restrict__ blockSum, int nb) {
    __shared__ int s[128];
    int t = threadIdx.x;
    int v = (t < nb) ? blockSum[t] : 0;
    s[t] = v;
    __syncthreads();
    for (int off = 1; off < 128; off <<= 1) {
        int x = (t >= off) ? s[t - off] : 0;
        __syncthreads();
        s[t] += x;
        __syncthreads();
    }
    if (t < nb) blockSum[t] = s[t] - v;
}

__global__ void scan_add(int* __restrict__ rp, const int* __restrict__ blockSum,
                         const int* __restrict__ cnt, int* __restrict__ cursor,
                         float* __restrict__ inv_deg, int n) {
    int gid = blockIdx.x * blockDim.x + threadIdx.x;
    if (gid < n) {
        int v = rp[gid] + blockSum[gid >> 10];
        rp[gid] = v;
        cursor[gid] = v;
        int d = cnt[gid];
        inv_deg[gid] = 1.0f / (float)(d > 1 ? d : 1);
        if (gid == n - 1) rp[n] = v + ((d + 7) & ~7);
    }
}

__global__ void init_gcur(int* __restrict__ gcur) {
    int t = threadIdx.x;
    gcur[t] = t * BUCKCAP;
}

// single-pass radix partition: LDS-reorder each 8192-edge chunk bucket-contiguously,
// then stream out dense runs -> coalesced global writes, no line ping-pong
__global__ __launch_bounds__(256) void partition_pairs(const int* __restrict__ src,
                                                       const int* __restrict__ dst,
                                                       int* __restrict__ gcur,
                                                       int2* __restrict__ pairs, int ne) {
    __shared__ int2 staged[ACHUNK];   // 64KB
    __shared__ int  dcache[ACHUNK];   // 32KB
    __shared__ int  hist[256], scanb[256], gbase[256];
    const int t = threadIdx.x;
    const int base = blockIdx.x * ACHUNK;
    const int n = min(ACHUNK, ne - base);

    hist[t] = 0;
    __syncthreads();
    for (int i = t; i < n; i += 256) {
        int d = dst[base + i];
        dcache[i] = d;
        atomicAdd(&hist[d >> 9], 1);
    }
    __syncthreads();

    // inclusive scan over 256 entries
    int v = hist[t];
    scanb[t] = v;
    __syncthreads();
    for (int off = 1; off < 256; off <<= 1) {
        int x = (t >= off) ? scanb[t - off] : 0;
        __syncthreads();
        scanb[t] += x;
        __syncthreads();
    }
    int excl = scanb[t] - v;
    __syncthreads();
    scanb[t] = excl;                                  // exclusive base of bucket t in LDS
    hist[t] = 0;                                      // reuse as running counter
    gbase[t] = (v > 0) ? atomicAdd(&gcur[t], v) : 0;  // reserve global run
    __syncthreads();

    // bucket-reorder chunk in LDS
    for (int i = t; i < n; i += 256) {
        int d = dcache[i];
        int b = d >> 9;
        int lp = scanb[b] + atomicAdd(&hist[b], 1);
        int2 pr; pr.x = src[base + i]; pr.y = d;
        staged[lp] = pr;
    }
    __syncthreads();

    // stream out: consecutive i within a bucket run -> consecutive global addrs
    for (int i = t; i < n; i += 256) {
        int2 pr = staged[i];
        int b = pr.y >> 9;
        pairs[gbase[b] + (i - scanb[b])] = pr;
    }
}

// node-exact fill: one block per bucket; scatter stays inside a ~47KB window
// (single block -> single XCD -> each line written back once)
__global__ __launch_bounds__(512) void fill_exact(const int* __restrict__ gcur,
                                                  const int2* __restrict__ pairs,
                                                  int* __restrict__ cursor,
                                                  int* __restrict__ ssrc) {
    int b = blockIdx.x;
    int end = gcur[b];
    for (int i = b * BUCKCAP + threadIdx.x; i < end; i += 512) {
        int2 pr = pairs[i];
        int p = atomicAdd(&cursor[pr.y], 1);
        ssrc[p] = pr.x;
    }
}

// fp32 [n][128] -> f16 [n][128]
__global__ void to_f16(const float* __restrict__ in, ushort* __restrict__ out, int n4) {
    int i = blockIdx.x * blockDim.x + threadIdx.x;
    if (i < n4) {
        float4 v = ((const float4*)in)[i];
        uint2 o;
        o.x = pk2h(v.x, v.y);
        o.y = pk2h(v.z, v.w);
        ((uint2*)out)[i] = o;
    }
}

// pack [Wl;Wr] into Bt f16 [n][k'=256]
__global__ void prep_w(const float* __restrict__ Wl, const float* __restrict__ Wr,
                       ushort* __restrict__ Bt) {
    int id = blockIdx.x * blockDim.x + threadIdx.x;
    if (id >= 32768) return;
    int nw = id & 127;
    int km = id >> 7;
    const float* W = (km < 128) ? Wl : Wr;
    int k = km & 127;
    Bt[(size_t)nw * 256 + km] = f2h(W[k * 128 + nw]);
}

// one wave per node; 8 gathers in flight; pad slots hit zero row NN
__global__ __launch_bounds__(256) void aggregate16(const ushort* __restrict__ feat,
                                                   const int* __restrict__ rp,
                                                   const int* __restrict__ ssrc,
                                                   const float* __restrict__ inv_deg,
                                                   ushort* __restrict__ outv, int n) {
    int wave = (blockIdx.x * blockDim.x + threadIdx.x) >> 6;
    int lane = threadIdx.x & 63;
    if (wave >= n) return;
    int beg = rp[wave], end = rp[wave + 1];
    const size_t loff = (size_t)(lane * 2);
    float s0 = 0.f, s1 = 0.f, s2 = 0.f, s3 = 0.f, s4 = 0.f, s5 = 0.f, s6 = 0.f, s7 = 0.f;
    int e = beg;
    if (e < end) {
        int4 c0 = *(const int4*)(ssrc + e);
        int4 c1 = *(const int4*)(ssrc + e + 4);
        for (; e < end; e += 8) {
            int4 d0 = c0, d1 = c1;
            int pn = (e + 8 < end) ? e + 8 : e;   // branchless prefetch addr
            c0 = *(const int4*)(ssrc + pn);
            c1 = *(const int4*)(ssrc + pn + 4);
            uint v0 = *(const uint*)(feat + (size_t)d0.x * 128 + loff);
            uint v1 = *(const uint*)(feat + (size_t)d0.y * 128 + loff);
            uint v2 = *(const uint*)(feat + (size_t)d0.z * 128 + loff);
            uint v3 = *(const uint*)(feat + (size_t)d0.w * 128 + loff);
            uint v4 = *(const uint*)(feat + (size_t)d1.x * 128 + loff);
            uint v5 = *(const uint*)(feat + (size_t)d1.y * 128 + loff);
            uint v6 = *(const uint*)(feat + (size_t)d1.z * 128 + loff);
            uint v7 = *(const uint*)(feat + (size_t)d1.w * 128 + loff);
            s0 += h2f(v0 & 0xffffu); s1 += h2f(v0 >> 16);
            s2 += h2f(v1 & 0xffffu); s3 += h2f(v1 >> 16);
            s0 += h2f(v2 & 0xffffu); s1 += h2f(v2 >> 16);
            s2 += h2f(v3 & 0xffffu); s3 += h2f(v3 >> 16);
            s4 += h2f(v4 & 0xffffu); s5 += h2f(v4 >> 16);
            s6 += h2f(v5 & 0xffffu); s7 += h2f(v5 >> 16);
            s4 += h2f(v6 & 0xffffu); s5 += h2f(v6 >> 16);
            s6 += h2f(v7 & 0xffffu); s7 += h2f(v7 >> 16);
        }
    }
    float id = inv_deg[wave];
    *(uint*)&outv[(size_t)wave * 128 + loff] =
        pk2h((s0 + s2 + s4 + s6) * id, (s1 + s3 + s5 + s7) * id);
}

// relu(Aop@Wl + Xop@Wr + bias) via f16 MFMA; 128x128 tile, 4 waves, K'=256
__global__ __launch_bounds__(256, 3) void sage_gemm_f16(const ushort* __restrict__ Aop,
                                                        const ushort* __restrict__ Xop,
                                                        const ushort* __restrict__ Bt,
                                                        const float* __restrict__ bias,
                                                        ushort* __restrict__ outH, int n) {
    __shared__ __align__(16) ushort sA[128 * 64];
    __shared__ __align__(16) ushort sB[128 * 64];
    const int t = threadIdx.x;
    const int l = t & 63;
    const int w = t >> 6;
    const int wr = (w >> 1) * 64, wc = (w & 1) * 64;
    const int rowBase = blockIdx.x * 128;
    const int sr = t >> 1, sh = t & 1;

    f32x4 acc[4][4];
#pragma unroll
    for (int i = 0; i < 4; ++i)
#pragma unroll
        for (int j = 0; j < 4; ++j) acc[i][j] = 0.0f;

    int4 rA[4], rB[4];
    int arow = rowBase + sr;
    if (arow >= n) arow = n - 1;

    auto gload = [&](int c) {
        const ushort* srcA = (c < 2) ? Aop : Xop;
        const int4* ga = (const int4*)(srcA + (size_t)arow * 128 + (c & 1) * 64 + sh * 32);
        const int4* gb = (const int4*)(Bt + (size_t)sr * 256 + c * 64 + sh * 32);
        rA[0] = ga[0]; rA[1] = ga[1]; rA[2] = ga[2]; rA[3] = ga[3];
        rB[0] = gb[0]; rB[1] = gb[1]; rB[2] = gb[2]; rB[3] = gb[3];
    };
    auto swrite = [&]() {
        char* bA = (char*)&sA[0] + sr * 128;
        char* bB = (char*)&sB[0] + sr * 128;
        const int swz = (sr & 7) << 4;
        const int b0 = sh * 64;
        *(int4*)(bA + ((b0 +  0) ^ swz)) = rA[0];
        *(int4*)(bA + ((b0 + 16) ^ swz)) = rA[1];
        *(int4*)(bA + ((b0 + 32) ^ swz)) = rA[2];
        *(int4*)(bA + ((b0 + 48) ^ swz)) = rA[3];
        *(int4*)(bB + ((b0 +  0) ^ swz)) = rB[0];
        *(int4*)(bB + ((b0 + 16) ^ swz)) = rB[1];
        *(int4*)(bB + ((b0 + 32) ^ swz)) = rB[2];
        *(int4*)(bB + ((b0 + 48) ^ swz)) = rB[3];
    };

    gload(0);
    swrite();
    __syncthreads();

    for (int c = 0; c < 4; ++c) {
        if (c < 3) gload(c + 1);

#pragma unroll
        for (int ks = 0; ks < 2; ++ks) {
            f16x8 af[4], bf[4];
#pragma unroll
            for (int i = 0; i < 4; ++i) {
                int r = wr + i * 16 + (l & 15);
                af[i] = *(const f16x8*)((char*)&sA[0] + r * 128 +
                                        ((ks * 64 + (l >> 4) * 16) ^ ((r & 7) << 4)));
                int cn = wc + i * 16 + (l & 15);
                bf[i] = *(const f16x8*)((char*)&sB[0] + cn * 128 +
                                        ((ks * 64 + (l >> 4) * 16) ^ ((cn & 7) << 4)));
            }
#pragma unroll
            for (int i = 0; i < 4; ++i)
#pragma unroll
                for (int j = 0; j < 4; ++j)
                    acc[i][j] = __builtin_amdgcn_mfma_f32_16x16x32_f16(af[i], bf[j], acc[i][j], 0, 0, 0);
        }

        __syncthreads();
        if (c < 3) {
            swrite();
            __syncthreads();
        }
    }

#pragma unroll
    for (int j = 0; j < 4; ++j) {
        int col = wc + j * 16 + (l & 15);
        float bb = bias[col];
#pragma unroll
        for (int i = 0; i < 4; ++i) {
#pragma unroll
            for (int q = 0; q < 4; ++q) {
                int row = rowBase + wr + i * 16 + (l >> 4) * 4 + q;
                if (row < n) {
                    float v = fmaxf(acc[i][j][q] + bb, 0.f);
                    outH[(size_t)row * 128 + col] = f2h(v);
                }
            }
        }
    }
}

__global__ void final_linear16(const ushort* __restrict__ H, const float* __restrict__ Wlin,
                               const float* __restrict__ blin, float* __restrict__ out, int n) {
    int r = blockIdx.x * blockDim.x + threadIdx.x;
    if (r >= n) return;
    float a0 = blin[0], a1 = blin[1];
    const ushort* hr = H + (size_t)r * 128;
    for (int c = 0; c < 128; c += 2) {
        uint v = *(const uint*)&hr[c];
        float h0 = h2f(v & 0xffffu);
        float h1 = h2f(v >> 16);
        float4 wv = *(const float4*)&Wlin[c * 2];
        a0 += h0 * wv.x + h1 * wv.z;
        a1 += h0 * wv.y + h1 * wv.w;
    }
    float2 o = {a0, a1};
    *(float2*)&out[(size_t)r * 2] = o;
}

extern "C" void kernel_launch(void* const* d_in, const int* in_sizes, int n_in,
                              void* d_out, int out_size, void* d_ws, size_t ws_size,
                              hipStream_t stream) {
    const float* x    = (const float*)d_in[0];
    const int*   ei   = (const int*)d_in[1];
    const float* W1l  = (const float*)d_in[2];
    const float* b1   = (const float*)d_in[3];
    const float* W1r  = (const float*)d_in[4];
    const float* W2l  = (const float*)d_in[5];
    const float* b2   = (const float*)d_in[6];
    const float* W2r  = (const float*)d_in[7];
    const float* Wlin = (const float*)d_in[8];
    const float* blin = (const float*)d_in[9];
    float* out = (float*)d_out;

    char* ws = (char*)d_ws;
    int*    cnt     = (int*)(ws + OFF_CNT);
    int*    row_ptr = (int*)(ws + OFF_RP);
    int*    cursor  = (int*)(ws + OFF_CUR);
    int*    bsum    = (int*)(ws + OFF_BS);
    float*  inv_deg = (float*)(ws + OFF_INVD);
    int*    gcur    = (int*)(ws + OFF_GCUR);
    int*    ssrc    = (int*)(ws + OFF_SSRC);
    int2*   pairs   = (int2*)(ws + OFF_PAIRS);
    ushort* B1c     = (ushort*)(ws + OFF_B1);
    ushort* B2c     = (ushort*)(ws + OFF_B2);
    ushort* x16     = (ushort*)(ws + OFF_X16);
    ushort* h16     = (ushort*)(ws + OFF_H16);
    ushort* agg16   = (ushort*)(ws + OFF_AGG);

    const int* src = ei;
    const int* dst = ei + NE;

    // weight packing + f16 conversion + dummy zero rows
    prep_w<<<128, 256, 0, stream>>>(W1l, W1r, B1c);
    prep_w<<<128, 256, 0, stream>>>(W2l, W2r, B2c);
    to_f16<<<(NN * 32 + 255) / 256, 256, 0, stream>>>(x, x16, NN * 32);
    zero_dummy<<<1, 128, 0, stream>>>(x16, h16);

    // CSR build: count -> scans -> radix partition -> exact fill
    zero_i32<<<(NN + 255) / 256, 256, 0, stream>>>(cnt, NN);
    fill_pad<<<(NEPAD + 255) / 256, 256, 0, stream>>>(ssrc);
    count_k<<<(NE + 255) / 256, 256, 0, stream>>>(dst, cnt, NE);
    scan_blocks<<<(NN + 1023) / 1024, 1024, 0, stream>>>(cnt, row_ptr, bsum, NN);
    scan_sums<<<1, 128, 0, stream>>>(bsum, (NN + 1023) / 1024);
    scan_add<<<(NN + 255) / 256, 256, 0, stream>>>(row_ptr, bsum, cnt, cursor, inv_deg, NN);
    init_gcur<<<1, 256, 0, stream>>>(gcur);
    partition_pairs<<<(NE + ACHUNK - 1) / ACHUNK, 256, 0, stream>>>(src, dst, gcur, pairs, NE);
    fill_exact<<<NBUCK, 512, 0, stream>>>(gcur, pairs, cursor, ssrc);

    // layer 1
    aggregate16<<<(NN * 64 + 255) / 256, 256, 0, stream>>>(x16, row_ptr, ssrc, inv_deg, agg16, NN);
    sage_gemm_f16<<<(NN + 127) / 128, 256, 0, stream>>>(agg16, x16, B1c, b1, h16, NN);

    // layer 2 (h2 goes into the dead x16 buffer)
    aggregate16<<<(NN * 64 + 255) / 256, 256, 0, stream>>>(h16, row_ptr, ssrc, inv_deg, agg16, NN);
    sage_gemm_f16<<<(NN + 127) / 128, 256, 0, stream>>>(agg16, h16, B2c, b2, x16, NN);

    // final linear
    final_linear16<<<(NN + 255) / 256, 256, 0, stream>>>(x16, Wlin, blin, out, NN);
}

// Round 6
// 298.467 us; speedup vs baseline: 2.0867x; 1.3687x over previous
//
#include <hip/hip_runtime.h>

#define NN 100000
#define NE 1600000
#define NBUCK 196       // ceil(NN/512) buckets of 512 nodes
#define BUCKCAP 11520   // packed-pair slots per bucket (avg 8192, +36 sigma)
#define SCAP 13312      // ssrc slots per bucket (>= bucket_total + 7*512 at +17 sigma)
#define ACHUNK 8192     // edges per partition block

typedef _Float16 f16x8 __attribute__((ext_vector_type(8)));
typedef float f32x4 __attribute__((ext_vector_type(4)));

// ---------------- workspace layout (bytes) ----------------
static const size_t OFF_GCUR  = 0;                         // 256 ints
static const size_t OFF_META  = 1024;                      // NN int4 {beg, padded_deg, inv_deg bits, 0}
static const size_t OFF_SSRC  = 1601024;                   // NBUCK*SCAP ints = 10.4MB
static const size_t OFF_PAIRS = 12037632;                  // NBUCK*BUCKCAP ints = 9.0MB
static const size_t OFF_B1    = 21069312;                  // 128x256 f16
static const size_t OFF_B2    = 21134848;
static const size_t OFF_X16   = 21200384;                  // (N+1)*128 f16 (row N = zeros)
static const size_t OFF_H16   = 46800640;                  // (N+1)*128 f16 (row N = zeros)
static const size_t OFF_AGG   = 72400896;                  // N*128 f16
// end 98.0MB

static __device__ inline float h2f(uint bits) {
    return (float)__builtin_bit_cast(_Float16, (ushort)bits);
}
static __device__ inline ushort f2h(float f) {
    return __builtin_bit_cast(ushort, (_Float16)f);
}
static __device__ inline uint pk2h(float a, float b) {
    return (uint)f2h(a) | ((uint)f2h(b) << 16);
}

__global__ void zero_dummy(ushort* __restrict__ a, ushort* __restrict__ b) {
    int t = threadIdx.x;
    a[(size_t)NN * 128 + t] = 0;
    b[(size_t)NN * 128 + t] = 0;
}

__global__ void init_gcur(int* __restrict__ gcur) {
    gcur[threadIdx.x] = threadIdx.x * BUCKCAP;
}

// single-pass radix partition: LDS-reorder each 8192-edge chunk bucket-contiguously,
// stream out dense runs of packed (src<<9 | dst&511) ints
__global__ __launch_bounds__(256) void partition_pairs(const int* __restrict__ src,
                                                       const int* __restrict__ dst,
                                                       int* __restrict__ gcur,
                                                       int* __restrict__ pairs, int ne) {
    __shared__ int2 staged[ACHUNK];   // 64KB {packed, dst}
    __shared__ int  dcache[ACHUNK];   // 32KB
    __shared__ int  hist[256], scanb[256], gbase[256];
    const int t = threadIdx.x;
    const int base = blockIdx.x * ACHUNK;
    const int n = min(ACHUNK, ne - base);

    hist[t] = 0;
    __syncthreads();
    for (int i = t; i < n; i += 256) {
        int d = dst[base + i];
        dcache[i] = d;
        atomicAdd(&hist[d >> 9], 1);
    }
    __syncthreads();

    int v = hist[t];
    scanb[t] = v;
    __syncthreads();
    for (int off = 1; off < 256; off <<= 1) {
        int x = (t >= off) ? scanb[t - off] : 0;
        __syncthreads();
        scanb[t] += x;
        __syncthreads();
    }
    int excl = scanb[t] - v;
    __syncthreads();
    scanb[t] = excl;
    hist[t] = 0;
    gbase[t] = (v > 0) ? atomicAdd(&gcur[t], v) : 0;
    __syncthreads();

    for (int i = t; i < n; i += 256) {
        int d = dcache[i];
        int b = d >> 9;
        int lp = scanb[b] + atomicAdd(&hist[b], 1);
        int2 pr;
        pr.x = (src[base + i] << 9) | (d & 511);
        pr.y = d;
        staged[lp] = pr;
    }
    __syncthreads();

    for (int i = t; i < n; i += 256) {
        int2 pr = staged[i];
        int b = pr.y >> 9;
        pairs[gbase[b] + (i - scanb[b])] = pr.x;
    }
}

// one block per bucket: LDS histogram -> LDS scan -> meta (int4/node) ->
// pad-fill private ssrc window -> LDS-cursor scatter (all window-local)
__global__ __launch_bounds__(512) void bucket_build(const int* __restrict__ gcur,
                                                    const int* __restrict__ pairs,
                                                    int4* __restrict__ meta,
                                                    int* __restrict__ ssrc) {
    __shared__ int s[512];
    __shared__ int exclA[512];
    __shared__ int cur[512];
    const int b = blockIdx.x;
    const int t = threadIdx.x;
    const int pbeg = b * BUCKCAP;
    const int pend = gcur[b];
    const int sbase = b * SCAP;

    cur[t] = 0;
    __syncthreads();
    for (int i = pbeg + t; i < pend; i += 512)
        atomicAdd(&cur[pairs[i] & 511], 1);
    __syncthreads();

    const int deg = cur[t];
    const int pc = (deg + 7) & ~7;
    s[t] = pc;
    __syncthreads();
    for (int off = 1; off < 512; off <<= 1) {
        int x = (t >= off) ? s[t - off] : 0;
        __syncthreads();
        s[t] += x;
        __syncthreads();
    }
    const int excl = s[t] - pc;
    exclA[t] = excl;
    const int node = (b << 9) + t;
    if (node < NN) {
        int4 m;
        m.x = sbase + excl;
        m.y = pc;
        m.z = __builtin_bit_cast(int, 1.0f / (float)(deg > 1 ? deg : 1));
        m.w = 0;
        meta[node] = m;
    }
    __syncthreads();
    const int total = s[511];
    // pad-fill the used window with dummy row NN (L2-local, coalesced)
    for (int i = t; i < total; i += 512)
        ssrc[sbase + i] = NN;
    cur[t] = 0;
    __syncthreads();
    // node-exact scatter within the ~52KB window
    for (int i = pbeg + t; i < pend; i += 512) {
        int p = pairs[i];
        int loc = p & 511;
        int pos = atomicAdd(&cur[loc], 1);
        ssrc[sbase + exclA[loc] + pos] = p >> 9;
    }
}

// fp32 [n][128] -> f16 [n][128]
__global__ void to_f16(const float* __restrict__ in, ushort* __restrict__ out, int n4) {
    int i = blockIdx.x * blockDim.x + threadIdx.x;
    if (i < n4) {
        float4 v = ((const float4*)in)[i];
        uint2 o;
        o.x = pk2h(v.x, v.y);
        o.y = pk2h(v.z, v.w);
        ((uint2*)out)[i] = o;
    }
}

// pack [Wl;Wr] into Bt f16 [n][k'=256]
__global__ void prep_w(const float* __restrict__ Wl, const float* __restrict__ Wr,
                       ushort* __restrict__ Bt) {
    int id = blockIdx.x * blockDim.x + threadIdx.x;
    if (id >= 32768) return;
    int nw = id & 127;
    int km = id >> 7;
    const float* W = (km < 128) ? Wl : Wr;
    int k = km & 127;
    Bt[(size_t)nw * 256 + km] = f2h(W[k * 128 + nw]);
}

// one wave per node; 8 gathers in flight; pad slots hit zero row NN
__global__ __launch_bounds__(256) void aggregate16(const ushort* __restrict__ feat,
                                                   const int4* __restrict__ meta,
                                                   const int* __restrict__ ssrc,
                                                   ushort* __restrict__ outv, int n) {
    int wave = (blockIdx.x * blockDim.x + threadIdx.x) >> 6;
    int lane = threadIdx.x & 63;
    if (wave >= n) return;
    const int4 m = meta[wave];
    const int beg = m.x, end = m.x + m.y;
    const float id = __builtin_bit_cast(float, m.z);
    const size_t loff = (size_t)(lane * 2);
    float s0 = 0.f, s1 = 0.f, s2 = 0.f, s3 = 0.f, s4 = 0.f, s5 = 0.f, s6 = 0.f, s7 = 0.f;
    int e = beg;
    if (e < end) {
        int4 c0 = *(const int4*)(ssrc + e);
        int4 c1 = *(const int4*)(ssrc + e + 4);
        for (; e < end; e += 8) {
            int4 d0 = c0, d1 = c1;
            int pn = (e + 8 < end) ? e + 8 : e;   // branchless prefetch addr
            c0 = *(const int4*)(ssrc + pn);
            c1 = *(const int4*)(ssrc + pn + 4);
            uint v0 = *(const uint*)(feat + (size_t)d0.x * 128 + loff);
            uint v1 = *(const uint*)(feat + (size_t)d0.y * 128 + loff);
            uint v2 = *(const uint*)(feat + (size_t)d0.z * 128 + loff);
            uint v3 = *(const uint*)(feat + (size_t)d0.w * 128 + loff);
            uint v4 = *(const uint*)(feat + (size_t)d1.x * 128 + loff);
            uint v5 = *(const uint*)(feat + (size_t)d1.y * 128 + loff);
            uint v6 = *(const uint*)(feat + (size_t)d1.z * 128 + loff);
            uint v7 = *(const uint*)(feat + (size_t)d1.w * 128 + loff);
            s0 += h2f(v0 & 0xffffu); s1 += h2f(v0 >> 16);
            s2 += h2f(v1 & 0xffffu); s3 += h2f(v1 >> 16);
            s0 += h2f(v2 & 0xffffu); s1 += h2f(v2 >> 16);
            s2 += h2f(v3 & 0xffffu); s3 += h2f(v3 >> 16);
            s4 += h2f(v4 & 0xffffu); s5 += h2f(v4 >> 16);
            s6 += h2f(v5 & 0xffffu); s7 += h2f(v5 >> 16);
            s4 += h2f(v6 & 0xffffu); s5 += h2f(v6 >> 16);
            s6 += h2f(v7 & 0xffffu); s7 += h2f(v7 >> 16);
        }
    }
    *(uint*)&outv[(size_t)wave * 128 + loff] =
        pk2h((s0 + s2 + s4 + s6) * id, (s1 + s3 + s5 + s7) * id);
}

// relu(Aop@Wl + Xop@Wr + bias) via f16 MFMA; 128x128 tile, 4 waves, K'=256
__global__ __launch_bounds__(256, 3) void sage_gemm_f16(const ushort* __restrict__ Aop,
                                                        const ushort* __restrict__ Xop,
                                                        const ushort* __restrict__ Bt,
                                                        const float* __restrict__ bias,
                                                        ushort* __restrict__ outH, int n) {
    __shared__ __align__(16) ushort sA[128 * 64];
    __shared__ __align__(16) ushort sB[128 * 64];
    const int t = threadIdx.x;
    const int l = t & 63;
    const int w = t >> 6;
    const int wr = (w >> 1) * 64, wc = (w & 1) * 64;
    const int rowBase = blockIdx.x * 128;
    const int sr = t >> 1, sh = t & 1;

    f32x4 acc[4][4];
#pragma unroll
    for (int i = 0; i < 4; ++i)
#pragma unroll
        for (int j = 0; j < 4; ++j) acc[i][j] = 0.0f;

    int4 rA[4], rB[4];
    int arow = rowBase + sr;
    if (arow >= n) arow = n - 1;

    auto gload = [&](int c) {
        const ushort* srcA = (c < 2) ? Aop : Xop;
        const int4* ga = (const int4*)(srcA + (size_t)arow * 128 + (c & 1) * 64 + sh * 32);
        const int4* gb = (const int4*)(Bt + (size_t)sr * 256 + c * 64 + sh * 32);
        rA[0] = ga[0]; rA[1] = ga[1]; rA[2] = ga[2]; rA[3] = ga[3];
        rB[0] = gb[0]; rB[1] = gb[1]; rB[2] = gb[2]; rB[3] = gb[3];
    };
    auto swrite = [&]() {
        char* bA = (char*)&sA[0] + sr * 128;
        char* bB = (char*)&sB[0] + sr * 128;
        const int swz = (sr & 7) << 4;
        const int b0 = sh * 64;
        *(int4*)(bA + ((b0 +  0) ^ swz)) = rA[0];
        *(int4*)(bA + ((b0 + 16) ^ swz)) = rA[1];
        *(int4*)(bA + ((b0 + 32) ^ swz)) = rA[2];
        *(int4*)(bA + ((b0 + 48) ^ swz)) = rA[3];
        *(int4*)(bB + ((b0 +  0) ^ swz)) = rB[0];
        *(int4*)(bB + ((b0 + 16) ^ swz)) = rB[1];
        *(int4*)(bB + ((b0 + 32) ^ swz)) = rB[2];
        *(int4*)(bB + ((b0 + 48) ^ swz)) = rB[3];
    };

    gload(0);
    swrite();
    __syncthreads();

    for (int c = 0; c < 4; ++c) {
        if (c < 3) gload(c + 1);

#pragma unroll
        for (int ks = 0; ks < 2; ++ks) {
            f16x8 af[4], bf[4];
#pragma unroll
            for (int i = 0; i < 4; ++i) {
                int r = wr + i * 16 + (l & 15);
                af[i] = *(const f16x8*)((char*)&sA[0] + r * 128 +
                                        ((ks * 64 + (l >> 4) * 16) ^ ((r & 7) << 4)));
                int cn = wc + i * 16 + (l & 15);
                bf[i] = *(const f16x8*)((char*)&sB[0] + cn * 128 +
                                        ((ks * 64 + (l >> 4) * 16) ^ ((cn & 7) << 4)));
            }
#pragma unroll
            for (int i = 0; i < 4; ++i)
#pragma unroll
                for (int j = 0; j < 4; ++j)
                    acc[i][j] = __builtin_amdgcn_mfma_f32_16x16x32_f16(af[i], bf[j], acc[i][j], 0, 0, 0);
        }

        __syncthreads();
        if (c < 3) {
            swrite();
            __syncthreads();
        }
    }

#pragma unroll
    for (int j = 0; j < 4; ++j) {
        int col = wc + j * 16 + (l & 15);
        float bb = bias[col];
#pragma unroll
        for (int i = 0; i < 4; ++i) {
#pragma unroll
            for (int q = 0; q < 4; ++q) {
                int row = rowBase + wr + i * 16 + (l >> 4) * 4 + q;
                if (row < n) {
                    float v = fmaxf(acc[i][j][q] + bb, 0.f);
                    outH[(size_t)row * 128 + col] = f2h(v);
                }
            }
        }
    }
}

__global__ void final_linear16(const ushort* __restrict__ H, const float* __restrict__ Wlin,
                               const float* __restrict__ blin, float* __restrict__ out, int n) {
    int r = blockIdx.x * blockDim.x + threadIdx.x;
    if (r >= n) return;
    float a0 = blin[0], a1 = blin[1];
    const ushort* hr = H + (size_t)r * 128;
    for (int c = 0; c < 128; c += 2) {
        uint v = *(const uint*)&hr[c];
        float h0 = h2f(v & 0xffffu);
        float h1 = h2f(v >> 16);
        float4 wv = *(const float4*)&Wlin[c * 2];
        a0 += h0 * wv.x + h1 * wv.z;
        a1 += h0 * wv.y + h1 * wv.w;
    }
    float2 o = {a0, a1};
    *(float2*)&out[(size_t)r * 2] = o;
}

extern "C" void kernel_launch(void* const* d_in, const int* in_sizes, int n_in,
                              void* d_out, int out_size, void* d_ws, size_t ws_size,
                              hipStream_t stream) {
    const float* x    = (const float*)d_in[0];
    const int*   ei   = (const int*)d_in[1];
    const float* W1l  = (const float*)d_in[2];
    const float* b1   = (const float*)d_in[3];
    const float* W1r  = (const float*)d_in[4];
    const float* W2l  = (const float*)d_in[5];
    const float* b2   = (const float*)d_in[6];
    const float* W2r  = (const float*)d_in[7];
    const float* Wlin = (const float*)d_in[8];
    const float* blin = (const float*)d_in[9];
    float* out = (float*)d_out;

    char* ws = (char*)d_ws;
    int*    gcur    = (int*)(ws + OFF_GCUR);
    int4*   meta    = (int4*)(ws + OFF_META);
    int*    ssrc    = (int*)(ws + OFF_SSRC);
    int*    pairs   = (int*)(ws + OFF_PAIRS);
    ushort* B1c     = (ushort*)(ws + OFF_B1);
    ushort* B2c     = (ushort*)(ws + OFF_B2);
    ushort* x16     = (ushort*)(ws + OFF_X16);
    ushort* h16     = (ushort*)(ws + OFF_H16);
    ushort* agg16   = (ushort*)(ws + OFF_AGG);

    const int* src = ei;
    const int* dst = ei + NE;

    // weight packing + f16 conversion + dummy zero rows
    prep_w<<<128, 256, 0, stream>>>(W1l, W1r, B1c);
    prep_w<<<128, 256, 0, stream>>>(W2l, W2r, B2c);
    to_f16<<<(NN * 32 + 255) / 256, 256, 0, stream>>>(x, x16, NN * 32);
    zero_dummy<<<1, 128, 0, stream>>>(x16, h16);

    // CSR build: radix partition -> per-bucket LDS count/scan/fill
    init_gcur<<<1, 256, 0, stream>>>(gcur);
    partition_pairs<<<(NE + ACHUNK - 1) / ACHUNK, 256, 0, stream>>>(src, dst, gcur, pairs, NE);
    bucket_build<<<NBUCK, 512, 0, stream>>>(gcur, pairs, meta, ssrc);

    // layer 1
    aggregate16<<<(NN * 64 + 255) / 256, 256, 0, stream>>>(x16, meta, ssrc, agg16, NN);
    sage_gemm_f16<<<(NN + 127) / 128, 256, 0, stream>>>(agg16, x16, B1c, b1, h16, NN);

    // layer 2 (h2 goes into the dead x16 buffer)
    aggregate16<<<(NN * 64 + 255) / 256, 256, 0, stream>>>(h16, meta, ssrc, agg16, NN);
    sage_gemm_f16<<<(NN + 127) / 128, 256, 0, stream>>>(agg16, h16, B2c, b2, x16, NN);

    // final linear
    final_linear16<<<(NN + 255) / 256, 256, 0, stream>>>(x16, Wlin, blin, out, NN);
}

// Round 8
// 269.768 us; speedup vs baseline: 2.3087x; 1.1064x over previous
//
#include <hip/hip_runtime.h>

#define NN 100000
#define NE 1600000
#define NBUCK 196       // ceil(NN/512) buckets of 512 nodes
#define BUCKCAP 11520   // packed-pair slots per bucket (avg 8192, +36 sigma)
#define SCAP 13312      // ssrc slots per bucket (>= bucket_total + 7*512 at +17 sigma)
#define ACHUNK 8192     // edges per partition block

typedef _Float16 f16x8 __attribute__((ext_vector_type(8)));
typedef float f32x4 __attribute__((ext_vector_type(4)));

// ---------------- workspace layout (bytes) ----------------
static const size_t OFF_GCUR  = 0;                         // 256 ints
static const size_t OFF_META  = 1024;                      // NN int4 {beg, padded_deg, inv_deg bits, 0}
static const size_t OFF_SSRC  = 1601024;                   // NBUCK*SCAP ints = 10.4MB
static const size_t OFF_PAIRS = 12037632;                  // NBUCK*BUCKCAP ints = 9.0MB
static const size_t OFF_B1    = 21069312;                  // 128x256 f16
static const size_t OFF_B2    = 21134848;
static const size_t OFF_X16   = 21200384;                  // (N+1)*128 f16 (row N = zeros)
static const size_t OFF_H16   = 46800640;                  // (N+1)*128 f16 (row N = zeros)
static const size_t OFF_AGG   = 72400896;                  // N*128 f16
// end 98.0MB

static __device__ inline float h2f(uint bits) {
    return (float)__builtin_bit_cast(_Float16, (ushort)bits);
}
static __device__ inline ushort f2h(float f) {
    return __builtin_bit_cast(ushort, (_Float16)f);
}
static __device__ inline uint pk2h(float a, float b) {
    return (uint)f2h(a) | ((uint)f2h(b) << 16);
}

__global__ void zero_dummy(ushort* __restrict__ a, ushort* __restrict__ b) {
    int t = threadIdx.x;
    a[(size_t)NN * 128 + t] = 0;
    b[(size_t)NN * 128 + t] = 0;
}

__global__ void init_gcur(int* __restrict__ gcur) {
    gcur[threadIdx.x] = threadIdx.x * BUCKCAP;
}

// single-pass radix partition: LDS-reorder each 8192-edge chunk bucket-contiguously,
// stream out dense runs of packed (src<<9 | dst&511) ints
__global__ __launch_bounds__(256) void partition_pairs(const int* __restrict__ src,
                                                       const int* __restrict__ dst,
                                                       int* __restrict__ gcur,
                                                       int* __restrict__ pairs, int ne) {
    __shared__ int2 staged[ACHUNK];   // 64KB {packed, dst}
    __shared__ int  dcache[ACHUNK];   // 32KB
    __shared__ int  hist[256], scanb[256], gbase[256];
    const int t = threadIdx.x;
    const int base = blockIdx.x * ACHUNK;
    const int n = min(ACHUNK, ne - base);

    hist[t] = 0;
    __syncthreads();
    for (int i = t; i < n; i += 256) {
        int d = dst[base + i];
        dcache[i] = d;
        atomicAdd(&hist[d >> 9], 1);
    }
    __syncthreads();

    int v = hist[t];
    scanb[t] = v;
    __syncthreads();
    for (int off = 1; off < 256; off <<= 1) {
        int x = (t >= off) ? scanb[t - off] : 0;
        __syncthreads();
        scanb[t] += x;
        __syncthreads();
    }
    int excl = scanb[t] - v;
    __syncthreads();
    scanb[t] = excl;
    hist[t] = 0;
    gbase[t] = (v > 0) ? atomicAdd(&gcur[t], v) : 0;
    __syncthreads();

    for (int i = t; i < n; i += 256) {
        int d = dcache[i];
        int b = d >> 9;
        int lp = scanb[b] + atomicAdd(&hist[b], 1);
        int2 pr;
        pr.x = (src[base + i] << 9) | (d & 511);
        pr.y = d;
        staged[lp] = pr;
    }
    __syncthreads();

    for (int i = t; i < n; i += 256) {
        int2 pr = staged[i];
        int b = pr.y >> 9;
        pairs[gbase[b] + (i - scanb[b])] = pr.x;
    }
}

// one block per bucket: LDS histogram -> scan -> meta -> pad-fill -> window-local scatter
__global__ __launch_bounds__(512) void bucket_build(const int* __restrict__ gcur,
                                                    const int* __restrict__ pairs,
                                                    int4* __restrict__ meta,
                                                    int* __restrict__ ssrc) {
    __shared__ int s[512];
    __shared__ int exclA[512];
    __shared__ int cur[512];
    const int b = blockIdx.x;
    const int t = threadIdx.x;
    const int pbeg = b * BUCKCAP;
    const int pend = gcur[b];
    const int sbase = b * SCAP;

    cur[t] = 0;
    __syncthreads();
    for (int i = pbeg + t; i < pend; i += 512)
        atomicAdd(&cur[pairs[i] & 511], 1);
    __syncthreads();

    const int deg = cur[t];
    const int pc = (deg + 7) & ~7;
    s[t] = pc;
    __syncthreads();
    for (int off = 1; off < 512; off <<= 1) {
        int x = (t >= off) ? s[t - off] : 0;
        __syncthreads();
        s[t] += x;
        __syncthreads();
    }
    const int excl = s[t] - pc;
    exclA[t] = excl;
    const int node = (b << 9) + t;
    if (node < NN) {
        int4 m;
        m.x = sbase + excl;
        m.y = pc;
        m.z = __builtin_bit_cast(int, 1.0f / (float)(deg > 1 ? deg : 1));
        m.w = 0;
        meta[node] = m;
    }
    __syncthreads();
    const int total = s[511];
    for (int i = t; i < total; i += 512)
        ssrc[sbase + i] = NN;
    cur[t] = 0;
    __syncthreads();
    for (int i = pbeg + t; i < pend; i += 512) {
        int p = pairs[i];
        int loc = p & 511;
        int pos = atomicAdd(&cur[loc], 1);
        ssrc[sbase + exclA[loc] + pos] = p >> 9;
    }
}

// fp32 [n][128] -> f16 [n][128]
__global__ void to_f16(const float* __restrict__ in, ushort* __restrict__ out, int n4) {
    int i = blockIdx.x * blockDim.x + threadIdx.x;
    if (i < n4) {
        float4 v = ((const float4*)in)[i];
        uint2 o;
        o.x = pk2h(v.x, v.y);
        o.y = pk2h(v.z, v.w);
        ((uint2*)out)[i] = o;
    }
}

// pack [Wl;Wr] into Bt f16 [n][k'=256]
__global__ void prep_w(const float* __restrict__ Wl, const float* __restrict__ Wr,
                       ushort* __restrict__ Bt) {
    int id = blockIdx.x * blockDim.x + threadIdx.x;
    if (id >= 32768) return;
    int nw = id & 127;
    int km = id >> 7;
    const float* W = (km < 128) ? Wl : Wr;
    int k = km & 127;
    Bt[(size_t)nw * 256 + km] = f2h(W[k * 128 + nw]);
}

// one wave per node; 8 gathers in flight; pad slots hit zero row NN
__global__ __launch_bounds__(256) void aggregate16(const ushort* __restrict__ feat,
                                                   const int4* __restrict__ meta,
                                                   const int* __restrict__ ssrc,
                                                   ushort* __restrict__ outv, int n) {
    int wave = (blockIdx.x * blockDim.x + threadIdx.x) >> 6;
    int lane = threadIdx.x & 63;
    if (wave >= n) return;
    const int4 m = meta[wave];
    const int beg = m.x, end = m.x + m.y;
    const float id = __builtin_bit_cast(float, m.z);
    const size_t loff = (size_t)(lane * 2);
    float s0 = 0.f, s1 = 0.f, s2 = 0.f, s3 = 0.f, s4 = 0.f, s5 = 0.f, s6 = 0.f, s7 = 0.f;
    int e = beg;
    if (e < end) {
        int4 c0 = *(const int4*)(ssrc + e);
        int4 c1 = *(const int4*)(ssrc + e + 4);
        for (; e < end; e += 8) {
            int4 d0 = c0, d1 = c1;
            int pn = (e + 8 < end) ? e + 8 : e;
            c0 = *(const int4*)(ssrc + pn);
            c1 = *(const int4*)(ssrc + pn + 4);
            uint v0 = *(const uint*)(feat + (size_t)d0.x * 128 + loff);
            uint v1 = *(const uint*)(feat + (size_t)d0.y * 128 + loff);
            uint v2 = *(const uint*)(feat + (size_t)d0.z * 128 + loff);
            uint v3 = *(const uint*)(feat + (size_t)d0.w * 128 + loff);
            uint v4 = *(const uint*)(feat + (size_t)d1.x * 128 + loff);
            uint v5 = *(const uint*)(feat + (size_t)d1.y * 128 + loff);
            uint v6 = *(const uint*)(feat + (size_t)d1.z * 128 + loff);
            uint v7 = *(const uint*)(feat + (size_t)d1.w * 128 + loff);
            s0 += h2f(v0 & 0xffffu); s1 += h2f(v0 >> 16);
            s2 += h2f(v1 & 0xffffu); s3 += h2f(v1 >> 16);
            s0 += h2f(v2 & 0xffffu); s1 += h2f(v2 >> 16);
            s2 += h2f(v3 & 0xffffu); s3 += h2f(v3 >> 16);
            s4 += h2f(v4 & 0xffffu); s5 += h2f(v4 >> 16);
            s6 += h2f(v5 & 0xffffu); s7 += h2f(v5 >> 16);
            s4 += h2f(v6 & 0xffffu); s5 += h2f(v6 >> 16);
            s6 += h2f(v7 & 0xffffu); s7 += h2f(v7 >> 16);
        }
    }
    *(uint*)&outv[(size_t)wave * 128 + loff] =
        pk2h((s0 + s2 + s4 + s6) * id, (s1 + s3 + s5 + s7) * id);
}

// ---- shared GEMM main loop (128x128 tile, 4 waves, K'=256, single 32KB buffer) ----
#define GEMM_MAIN_LOOP(SMEM, ACC)                                                      \
    ushort* sA = (ushort*)(SMEM);                                                      \
    ushort* sB = (ushort*)((SMEM) + 16384);                                            \
    const int l = t & 63;                                                              \
    const int w = t >> 6;                                                              \
    const int wr = (w >> 1) * 64, wc = (w & 1) * 64;                                   \
    const int sr = t >> 1, sh = t & 1;                                                 \
    int4 rA[4], rB[4];                                                                 \
    int arow = rowBase + sr;                                                           \
    if (arow >= n) arow = n - 1;                                                       \
    auto gload = [&](int c) {                                                          \
        const ushort* srcA = (c < 2) ? Aop : Xop;                                      \
        const int4* ga = (const int4*)(srcA + (size_t)arow * 128 + (c & 1) * 64 + sh * 32); \
        const int4* gb = (const int4*)(Bt + (size_t)sr * 256 + c * 64 + sh * 32);      \
        rA[0] = ga[0]; rA[1] = ga[1]; rA[2] = ga[2]; rA[3] = ga[3];                    \
        rB[0] = gb[0]; rB[1] = gb[1]; rB[2] = gb[2]; rB[3] = gb[3];                    \
    };                                                                                 \
    auto swrite = [&]() {                                                              \
        char* bA = (char*)sA + sr * 128;                                               \
        char* bB = (char*)sB + sr * 128;                                               \
        const int swz = (sr & 7) << 4;                                                 \
        const int b0 = sh * 64;                                                        \
        *(int4*)(bA + ((b0 +  0) ^ swz)) = rA[0];                                      \
        *(int4*)(bA + ((b0 + 16) ^ swz)) = rA[1];                                      \
        *(int4*)(bA + ((b0 + 32) ^ swz)) = rA[2];                                      \
        *(int4*)(bA + ((b0 + 48) ^ swz)) = rA[3];                                      \
        *(int4*)(bB + ((b0 +  0) ^ swz)) = rB[0];                                      \
        *(int4*)(bB + ((b0 + 16) ^ swz)) = rB[1];                                      \
        *(int4*)(bB + ((b0 + 32) ^ swz)) = rB[2];                                      \
        *(int4*)(bB + ((b0 + 48) ^ swz)) = rB[3];                                      \
    };                                                                                 \
    gload(0);                                                                          \
    swrite();                                                                          \
    __syncthreads();                                                                   \
    for (int c = 0; c < 4; ++c) {                                                      \
        if (c < 3) gload(c + 1);                                                       \
        _Pragma("unroll")                                                              \
        for (int ks = 0; ks < 2; ++ks) {                                               \
            f16x8 af[4], bf[4];                                                        \
            _Pragma("unroll")                                                          \
            for (int i = 0; i < 4; ++i) {                                              \
                int r = wr + i * 16 + (l & 15);                                        \
                af[i] = *(const f16x8*)((char*)sA + r * 128 +                          \
                                        ((ks * 64 + (l >> 4) * 16) ^ ((r & 7) << 4))); \
                int cn = wc + i * 16 + (l & 15);                                       \
                bf[i] = *(const f16x8*)((char*)sB + cn * 128 +                         \
                                        ((ks * 64 + (l >> 4) * 16) ^ ((cn & 7) << 4)));\
            }                                                                          \
            _Pragma("unroll")                                                          \
            for (int i = 0; i < 4; ++i)                                                \
                _Pragma("unroll")                                                      \
                for (int j = 0; j < 4; ++j)                                            \
                    ACC[i][j] = __builtin_amdgcn_mfma_f32_16x16x32_f16(af[i], bf[j], ACC[i][j], 0, 0, 0); \
        }                                                                              \
        __syncthreads();                                                               \
        if (c < 3) {                                                                   \
            swrite();                                                                  \
            __syncthreads();                                                           \
        }                                                                              \
    }

// layer-1 GEMM: relu(A@Wl + X@Wr + b) -> h16, LDS-staged coalesced f16 store
__global__ __launch_bounds__(256, 4) void sage_gemm_f16(const ushort* __restrict__ Aop,
                                                        const ushort* __restrict__ Xop,
                                                        const ushort* __restrict__ Bt,
                                                        const float* __restrict__ bias,
                                                        ushort* __restrict__ outH, int n) {
    __shared__ __align__(16) char smem[32768];
    const int t = threadIdx.x;
    const int rowBase = blockIdx.x * 128;

    f32x4 acc[4][4];
#pragma unroll
    for (int i = 0; i < 4; ++i)
#pragma unroll
        for (int j = 0; j < 4; ++j) acc[i][j] = 0.0f;

    GEMM_MAIN_LOOP(smem, acc)

    // stage output tile in LDS as f16
    ushort* sOut = (ushort*)smem;
#pragma unroll
    for (int j = 0; j < 4; ++j) {
        int col = wc + j * 16 + (l & 15);
        float bb = bias[col];
#pragma unroll
        for (int i = 0; i < 4; ++i)
#pragma unroll
            for (int q = 0; q < 4; ++q) {
                int row = wr + i * 16 + (l >> 4) * 4 + q;
                sOut[row * 128 + col] = f2h(fmaxf(acc[i][j][q] + bb, 0.f));
            }
    }
    __syncthreads();

    // coalesced copy-out: FULL 32KB tile = 8 passes of 256 threads x 16B
    // (round-7 bug: k<4 only wrote rows 0-63)
#pragma unroll
    for (int k = 0; k < 8; ++k) {
        int row = k * 16 + (t >> 4);
        int4 v = *(const int4*)(smem + k * 4096 + t * 16);
        if (rowBase + row < n)
            *(int4*)(outH + (size_t)(rowBase + row) * 128 + (t & 15) * 8) = v;
    }
}

// layer-2 GEMM with fused final linear: out = relu(A@W2l + H@W2r + b2) @ Wlin + blin
__global__ __launch_bounds__(256, 4) void sage_gemm_final(const ushort* __restrict__ Aop,
                                                          const ushort* __restrict__ Xop,
                                                          const ushort* __restrict__ Bt,
                                                          const float* __restrict__ bias,
                                                          const float* __restrict__ Wlin,
                                                          const float* __restrict__ blin,
                                                          float* __restrict__ out, int n) {
    __shared__ __align__(16) char smem[32768];
    const int t = threadIdx.x;
    const int rowBase = blockIdx.x * 128;

    f32x4 acc[4][4];
#pragma unroll
    for (int i = 0; i < 4; ++i)
#pragma unroll
        for (int j = 0; j < 4; ++j) acc[i][j] = 0.0f;

    GEMM_MAIN_LOOP(smem, acc)

    // per-thread partial dot with Wlin over its 4 columns
    float bb[4], wl0[4], wl1[4];
#pragma unroll
    for (int j = 0; j < 4; ++j) {
        int col = wc + j * 16 + (l & 15);
        bb[j]  = bias[col];
        float2 wv = *(const float2*)&Wlin[col * 2];
        wl0[j] = wv.x;
        wl1[j] = wv.y;
    }
    float* sP = (float*)smem;   // [128 rows][32 partials][2] = 32KB
    const int p = (w & 1) * 16 + (l & 15);
#pragma unroll
    for (int i = 0; i < 4; ++i)
#pragma unroll
        for (int q = 0; q < 4; ++q) {
            int row = wr + i * 16 + (l >> 4) * 4 + q;
            float p0 = 0.f, p1 = 0.f;
#pragma unroll
            for (int j = 0; j < 4; ++j) {
                float v = fmaxf(acc[i][j][q] + bb[j], 0.f);
                p0 += v * wl0[j];
                p1 += v * wl1[j];
            }
            sP[row * 64 + p * 2 + 0] = p0;
            sP[row * 64 + p * 2 + 1] = p1;
        }
    __syncthreads();

    // 256 threads reduce 256 outputs (128 rows x 2 comps)
    const int row = t >> 1, comp = t & 1;
    float s = 0.f;
#pragma unroll
    for (int k = 0; k < 32; ++k)
        s += sP[row * 64 + k * 2 + comp];
    if (rowBase + row < n)
        out[(size_t)(rowBase + row) * 2 + comp] = s + blin[comp];
}

extern "C" void kernel_launch(void* const* d_in, const int* in_sizes, int n_in,
                              void* d_out, int out_size, void* d_ws, size_t ws_size,
                              hipStream_t stream) {
    const float* x    = (const float*)d_in[0];
    const int*   ei   = (const int*)d_in[1];
    const float* W1l  = (const float*)d_in[2];
    const float* b1   = (const float*)d_in[3];
    const float* W1r  = (const float*)d_in[4];
    const float* W2l  = (const float*)d_in[5];
    const float* b2   = (const float*)d_in[6];
    const float* W2r  = (const float*)d_in[7];
    const float* Wlin = (const float*)d_in[8];
    const float* blin = (const float*)d_in[9];
    float* out = (float*)d_out;

    char* ws = (char*)d_ws;
    int*    gcur    = (int*)(ws + OFF_GCUR);
    int4*   meta    = (int4*)(ws + OFF_META);
    int*    ssrc    = (int*)(ws + OFF_SSRC);
    int*    pairs   = (int*)(ws + OFF_PAIRS);
    ushort* B1c     = (ushort*)(ws + OFF_B1);
    ushort* B2c     = (ushort*)(ws + OFF_B2);
    ushort* x16     = (ushort*)(ws + OFF_X16);
    ushort* h16     = (ushort*)(ws + OFF_H16);
    ushort* agg16   = (ushort*)(ws + OFF_AGG);

    const int* src = ei;
    const int* dst = ei + NE;

    // weight packing + f16 conversion + dummy zero rows
    prep_w<<<128, 256, 0, stream>>>(W1l, W1r, B1c);
    prep_w<<<128, 256, 0, stream>>>(W2l, W2r, B2c);
    to_f16<<<(NN * 32 + 255) / 256, 256, 0, stream>>>(x, x16, NN * 32);
    zero_dummy<<<1, 128, 0, stream>>>(x16, h16);

    // CSR build: radix partition -> per-bucket LDS count/scan/fill
    init_gcur<<<1, 256, 0, stream>>>(gcur);
    partition_pairs<<<(NE + ACHUNK - 1) / ACHUNK, 256, 0, stream>>>(src, dst, gcur, pairs, NE);
    bucket_build<<<NBUCK, 512, 0, stream>>>(gcur, pairs, meta, ssrc);

    // layer 1
    aggregate16<<<(NN * 64 + 255) / 256, 256, 0, stream>>>(x16, meta, ssrc, agg16, NN);
    sage_gemm_f16<<<(NN + 127) / 128, 256, 0, stream>>>(agg16, x16, B1c, b1, h16, NN);

    // layer 2 + fused final linear (h2 never materialized)
    aggregate16<<<(NN * 64 + 255) / 256, 256, 0, stream>>>(h16, meta, ssrc, agg16, NN);
    sage_gemm_final<<<(NN + 127) / 128, 256, 0, stream>>>(agg16, h16, B2c, b2, Wlin, blin, out, NN);
}